// Round 1
// baseline (445.481 us; speedup 1.0000x reference)
//
#include <hip/hip_runtime.h>
#include <stdint.h>

#define NANCH 17064
#define BATCH 16
#define NCLS 80
#define KDET 1000
#define SCORE_THR 0.05f
#define IOU_THR 0.6f

typedef unsigned long long u64;
typedef unsigned int u32;

__device__ __forceinline__ float sigf(float x) { return 1.0f / (1.0f + expf(-x)); }

__device__ __forceinline__ void decode_anchor(int n, int& l, int& h, int& w) {
  if (n < 12800)      { l = 0; h = n >> 7;               w = n & 127; }
  else if (n < 16000) { l = 1; int r = n - 12800; h = r >> 6; w = r & 63; }
  else if (n < 16800) { l = 2; int r = n - 16000; h = r >> 5; w = r & 31; }
  else if (n < 17008) { l = 3; int r = n - 16800; h = r >> 4; w = r & 15; }
  else                { l = 4; int r = n - 17008; h = r >> 3; w = r & 7; }
}

// ---------------- kernel 1: per-anchor scores ----------------
__global__ __launch_bounds__(256) void k_score(
    const float* __restrict__ cls0, const float* __restrict__ ctr0,
    const float* __restrict__ cls1, const float* __restrict__ ctr1,
    const float* __restrict__ cls2, const float* __restrict__ ctr2,
    const float* __restrict__ cls3, const float* __restrict__ ctr3,
    const float* __restrict__ cls4, const float* __restrict__ ctr4,
    u32* __restrict__ sb, unsigned char* __restrict__ cl8)
{
  int n = blockIdx.x * blockDim.x + threadIdx.x;
  if (n >= NANCH) return;
  int b = blockIdx.y;
  int l, h, w; decode_anchor(n, l, h, w);
  const float* cp; const float* tp; int H, W;
  switch (l) {
    case 0: cp = cls0; tp = ctr0; H = 100; W = 128; break;
    case 1: cp = cls1; tp = ctr1; H = 50;  W = 64;  break;
    case 2: cp = cls2; tp = ctr2; H = 25;  W = 32;  break;
    case 3: cp = cls3; tp = ctr3; H = 13;  W = 16;  break;
    default: cp = cls4; tp = ctr4; H = 7;  W = 8;   break;
  }
  int hw = H * W;
  const float* base = cp + (size_t)b * NCLS * hw + h * W + w;
  // argmax over sigmoid values (matches ref tie semantics: first occurrence, strict >)
  float ms = -1.0f; int am = 0;
  for (int c = 0; c < NCLS; ++c) {
    float s = sigf(base[(size_t)c * hw]);
    if (s > ms) { ms = s; am = c; }
  }
  float ct = sigf(tp[(size_t)b * hw + h * W + w]);
  float score = ms * ct;
  sb[b * NANCH + n] = __float_as_uint(score);
  cl8[b * NANCH + n] = (unsigned char)am;
}

// ---------------- kernel 2: topk + NMS + outputs, one block per batch ----------------
__global__ __launch_bounds__(1024) void k_select(
    const float* __restrict__ reg0, const float* __restrict__ reg1,
    const float* __restrict__ reg2, const float* __restrict__ reg3,
    const float* __restrict__ reg4,
    const u32* __restrict__ sb, const unsigned char* __restrict__ cl8,
    u64* __restrict__ mat, float* __restrict__ out)
{
  __shared__ u32 hist[1024];
  __shared__ u32 ssum[1024];
  __shared__ float red[1024];
  __shared__ u64 keys[2048];
  __shared__ float4 nbx[1024];
  __shared__ float areaS[1024];
  __shared__ u64 invw[16];
  __shared__ u64 supw[16];
  __shared__ int s_T1, s_above, s_T2, s_cnt;

  const int tid = threadIdx.x;
  const int b = blockIdx.x;
  const u32* sbb = sb + b * NANCH;

  // ---- Phase 1: coarse histogram on bits[31:22] + suffix scan -> T1
  hist[tid] = 0;
  __syncthreads();
  for (int n = tid; n < NANCH; n += 1024) atomicAdd(&hist[sbb[n] >> 22], 1u);
  __syncthreads();
  ssum[tid] = hist[tid];
  __syncthreads();
  for (int off = 1; off < 1024; off <<= 1) {
    u32 a = ssum[tid];
    u32 c = (tid + off < 1024) ? ssum[tid + off] : 0u;
    __syncthreads();
    ssum[tid] = a + c;
    __syncthreads();
  }
  {
    u32 S = ssum[tid];
    u32 Sn = (tid < 1023) ? ssum[tid + 1] : 0u;
    if (S >= (u32)KDET && Sn < (u32)KDET) { s_T1 = tid; s_above = (int)Sn; }
  }
  __syncthreads();
  const int T1 = s_T1; const int above = s_above;

  // ---- Phase 2: fine histogram on bits[21:12] within bin T1 -> T2
  hist[tid] = 0;
  __syncthreads();
  for (int n = tid; n < NANCH; n += 1024) {
    u32 bits = sbb[n];
    if ((int)(bits >> 22) == T1) atomicAdd(&hist[(bits >> 12) & 1023u], 1u);
  }
  __syncthreads();
  ssum[tid] = hist[tid];
  __syncthreads();
  for (int off = 1; off < 1024; off <<= 1) {
    u32 a = ssum[tid];
    u32 c = (tid + off < 1024) ? ssum[tid + off] : 0u;
    __syncthreads();
    ssum[tid] = a + c;
    __syncthreads();
  }
  {
    int S = above + (int)ssum[tid];
    int Sn = above + ((tid < 1023) ? (int)ssum[tid + 1] : 0);
    if (S >= KDET && Sn < KDET) s_T2 = tid;
  }
  if (tid == 0) s_cnt = 0;
  keys[tid] = 0ull; keys[tid + 1024] = 0ull;
  __syncthreads();
  const int T2 = s_T2;

  // ---- Phase 3: collect candidates (key = score_bits<<32 | ~n : desc score, asc index)
  for (int n = tid; n < NANCH; n += 1024) {
    u32 bits = sbb[n];
    int c1 = (int)(bits >> 22);
    bool cand = (c1 > T1) || (c1 == T1 && (int)((bits >> 12) & 1023u) >= T2);
    if (cand) {
      int pos = atomicAdd(&s_cnt, 1);
      if (pos < 2048) keys[pos] = ((u64)bits << 32) | (u64)(u32)(~(u32)n);
    }
  }
  __syncthreads();

  // ---- Phase 4: bitonic sort 2048 keys, descending
  for (int k2 = 2; k2 <= 2048; k2 <<= 1) {
    for (int j = k2 >> 1; j > 0; j >>= 1) {
      int i = ((tid & ~(j - 1)) << 1) | (tid & (j - 1));
      int p = i | j;
      u64 a = keys[i], bb = keys[p];
      bool up = (i & k2) == 0;
      bool sw = up ? (a < bb) : (a > bb);
      if (sw) { keys[i] = bb; keys[p] = a; }
      __syncthreads();
    }
  }

  // ---- Phase 5: extract top-1000, recompute class + box
  float score = 0.0f; int clsv = 0; bool valid = false;
  float bx0 = 0, bx1 = 0, bx2 = 0, bx3 = 0;
  if (tid < KDET) {
    u64 key = keys[tid];
    if (key != 0ull) {
      u32 bits = (u32)(key >> 32);
      int n = (int)(~(u32)(key & 0xFFFFFFFFull));
      score = __uint_as_float(bits);
      clsv = (int)cl8[b * NANCH + n] + 1;
      int l, h, w; decode_anchor(n, l, h, w);
      const float* rp; int H, W, ST, HF;
      switch (l) {
        case 0: rp = reg0; H = 100; W = 128; ST = 8;   HF = 4;  break;
        case 1: rp = reg1; H = 50;  W = 64;  ST = 16;  HF = 8;  break;
        case 2: rp = reg2; H = 25;  W = 32;  ST = 32;  HF = 16; break;
        case 3: rp = reg3; H = 13;  W = 16;  ST = 64;  HF = 32; break;
        default: rp = reg4; H = 7;  W = 8;   ST = 128; HF = 64; break;
      }
      int hw = H * W;
      float cx = (float)(w * ST + HF);
      float cy = (float)(h * ST + HF);
      const float* rb = rp + (size_t)b * 4 * hw + h * W + w;
      float r0 = rb[0], r1 = rb[hw], r2 = rb[2 * hw], r3 = rb[3 * hw];
      bx0 = cx - r0; bx1 = cy - r1; bx2 = cx + r2; bx3 = cy + r3;
      valid = (score >= SCORE_THR);
    }
  }

  // ---- Phase 6: max_coord over ALL topk boxes (valid or not, per ref)
  float m = -3.4e38f;
  if (tid < KDET) m = fmaxf(fmaxf(bx0, bx1), fmaxf(bx2, bx3));
  red[tid] = m;
  __syncthreads();
  for (int s = 512; s > 0; s >>= 1) {
    if (tid < s) red[tid] = fmaxf(red[tid], red[tid + s]);
    __syncthreads();
  }
  const float maxc = red[0];
  __syncthreads();

  // ---- Phase 7: class-offset NMS boxes + areas into LDS; invalid-word ballots
  {
    float o = (float)clsv * (maxc + 1.0f);
    float x1 = bx0 + o, y1 = bx1 + o, x2 = bx2 + o, y2 = bx3 + o;
    if (tid >= KDET) { x1 = y1 = x2 = y2 = 0.0f; }
    nbx[tid] = make_float4(x1, y1, x2, y2);
    areaS[tid] = (x2 - x1 + 1.0f) * (y2 - y1 + 1.0f);
  }
  {
    bool inv = (tid >= KDET) || (!valid);
    u64 mball = __ballot(inv);
    if ((tid & 63) == 0) invw[tid >> 6] = mball;
  }
  __syncthreads();

  // ---- Phase 8: suppression matrix (bit j of row i: iou(i,j)>thr && j>i)
  {
    int wv = tid >> 6, lane = tid & 63;
    u64* mrow = mat + (size_t)b * (KDET * 16);
    for (int i = wv; i < KDET; i += 16) {
      float4 bi = nbx[i];
      float ai = areaS[i];
      for (int wc = 0; wc < 16; ++wc) {
        int j = (wc << 6) + lane;
        float4 bj = nbx[j];
        float xmin = fmaxf(bi.x, bj.x);
        float ymin = fmaxf(bi.y, bj.y);
        float xmax = fminf(bi.z, bj.z);
        float ymax = fminf(bi.w, bj.w);
        float iw = fmaxf(xmax - xmin, 0.0f);
        float ih = fmaxf(ymax - ymin, 0.0f);
        float inter = iw * ih;
        float iou = inter / ((ai + areaS[j]) - inter);
        bool p = (j > i) && (j < KDET) && (iou > IOU_THR);
        u64 mm = __ballot(p);
        if (lane == 0) mrow[i * 16 + wc] = mm;
      }
    }
  }
  __threadfence();
  __syncthreads();

  // ---- Phase 9: serial greedy scan on wave 0 (16 lanes hold sup words), prefetch depth 8
  if (tid < 64) {
    int lane = tid;
    u64 sup = (lane < 16) ? invw[lane] : 0ull;
    const u64* mrow = mat + (size_t)b * (KDET * 16);
    u64 buf[8];
#pragma unroll
    for (int p = 0; p < 8; ++p) buf[p] = (lane < 16) ? mrow[p * 16 + lane] : 0ull;
    for (int base = 0; base < KDET; base += 8) {
#pragma unroll
      for (int p = 0; p < 8; ++p) {
        int i = base + p;
        u64 sw = __shfl(sup, i >> 6);
        bool keep = ((sw >> (i & 63)) & 1ull) == 0ull;
        u64 row = buf[p];
        int ip = i + 8;
        buf[p] = (ip < KDET && lane < 16) ? mrow[ip * 16 + lane] : 0ull;
        if (keep) sup |= row;
      }
    }
    if (lane < 16) supw[lane] = sup;
  }
  __syncthreads();

  // ---- Phase 10: outputs (scores | classes | boxes), zeros where not kept
  if (tid < KDET) {
    bool kp = valid && (((supw[tid >> 6] >> (tid & 63)) & 1ull) == 0ull);
    int o1 = b * KDET + tid;
    out[o1] = kp ? score : 0.0f;
    out[BATCH * KDET + o1] = kp ? (float)clsv : 0.0f;
    float* ob = out + 2 * BATCH * KDET + (size_t)o1 * 4;
    ob[0] = kp ? bx0 : 0.0f;
    ob[1] = kp ? bx1 : 0.0f;
    ob[2] = kp ? bx2 : 0.0f;
    ob[3] = kp ? bx3 : 0.0f;
  }
}

extern "C" void kernel_launch(void* const* d_in, const int* in_sizes, int n_in,
                              void* d_out, int out_size, void* d_ws, size_t ws_size,
                              hipStream_t stream) {
  const float* cls[5]; const float* ctr[5]; const float* reg[5];
  for (int i = 0; i < 5; ++i) {
    cls[i] = (const float*)d_in[3 * i + 0];
    ctr[i] = (const float*)d_in[3 * i + 1];
    reg[i] = (const float*)d_in[3 * i + 2];
  }
  char* ws = (char*)d_ws;
  u32* sb = (u32*)ws;                                   // 16*17064*4   = 1,092,096 B
  unsigned char* cl8 = (unsigned char*)(ws + 1092096);  // 16*17064    =   273,024 B
  u64* mat = (u64*)(ws + 1365120);                      // 16*1000*16*8 = 2,048,000 B

  dim3 g1((NANCH + 255) / 256, BATCH);
  k_score<<<g1, 256, 0, stream>>>(cls[0], ctr[0], cls[1], ctr[1], cls[2], ctr[2],
                                  cls[3], ctr[3], cls[4], ctr[4], sb, cl8);
  k_select<<<BATCH, 1024, 0, stream>>>(reg[0], reg[1], reg[2], reg[3], reg[4],
                                       sb, cl8, mat, (float*)d_out);
}

// Round 2
// 358.381 us; speedup vs baseline: 1.2430x; 1.2430x over previous
//
#include <hip/hip_runtime.h>
#include <stdint.h>

#define NANCH 17064
#define BATCH 16
#define NCLS 80
#define KDET 1000
#define SCORE_THR 0.05f
#define IOU_THR 0.6f

typedef unsigned long long u64;
typedef unsigned int u32;

__device__ __forceinline__ float sigf(float x) { return 1.0f / (1.0f + expf(-x)); }

__device__ __forceinline__ void decode_anchor(int n, int& l, int& h, int& w) {
  if (n < 12800)      { l = 0; h = n >> 7;               w = n & 127; }
  else if (n < 16000) { l = 1; int r = n - 12800; h = r >> 6; w = r & 63; }
  else if (n < 16800) { l = 2; int r = n - 16000; h = r >> 5; w = r & 31; }
  else if (n < 17008) { l = 3; int r = n - 16800; h = r >> 4; w = r & 15; }
  else                { l = 4; int r = n - 17008; h = r >> 3; w = r & 7; }
}

// ---------------- kernel 1: per-anchor scores ----------------
__global__ __launch_bounds__(256) void k_score(
    const float* __restrict__ cls0, const float* __restrict__ ctr0,
    const float* __restrict__ cls1, const float* __restrict__ ctr1,
    const float* __restrict__ cls2, const float* __restrict__ ctr2,
    const float* __restrict__ cls3, const float* __restrict__ ctr3,
    const float* __restrict__ cls4, const float* __restrict__ ctr4,
    u32* __restrict__ sb, unsigned char* __restrict__ cl8)
{
  int n = blockIdx.x * blockDim.x + threadIdx.x;
  if (n >= NANCH) return;
  int b = blockIdx.y;
  int l, h, w; decode_anchor(n, l, h, w);
  const float* cp; const float* tp; int H, W;
  switch (l) {
    case 0: cp = cls0; tp = ctr0; H = 100; W = 128; break;
    case 1: cp = cls1; tp = ctr1; H = 50;  W = 64;  break;
    case 2: cp = cls2; tp = ctr2; H = 25;  W = 32;  break;
    case 3: cp = cls3; tp = ctr3; H = 13;  W = 16;  break;
    default: cp = cls4; tp = ctr4; H = 7;  W = 8;   break;
  }
  int hw = H * W;
  const float* base = cp + (size_t)b * NCLS * hw + h * W + w;
  float ms = -1.0f; int am = 0;
  for (int c = 0; c < NCLS; ++c) {
    float s = sigf(base[(size_t)c * hw]);
    if (s > ms) { ms = s; am = c; }
  }
  float ct = sigf(tp[(size_t)b * hw + h * W + w]);
  float score = ms * ct;
  sb[b * NANCH + n] = __float_as_uint(score);
  cl8[b * NANCH + n] = (unsigned char)am;
}

// ---------------- kernel 2: top-1000 via radix-select + rank-by-counting ----------------
__global__ __launch_bounds__(1024) void k_topk(
    const float* __restrict__ reg0, const float* __restrict__ reg1,
    const float* __restrict__ reg2, const float* __restrict__ reg3,
    const float* __restrict__ reg4,
    const u32* __restrict__ sb, const unsigned char* __restrict__ cl8,
    float4* __restrict__ nbxG, float* __restrict__ areaG,
    float* __restrict__ scoreG, int* __restrict__ clsG, float4* __restrict__ boxG)
{
  __shared__ u32 hist[1024];
  __shared__ u32 wtot[16];
  __shared__ float wmaxS[16];
  __shared__ u64 keys[2048];
  __shared__ int s_T1, s_above, s_T2, s_cnt;

  const int tid = threadIdx.x;
  const int b = blockIdx.x;
  const int lane = tid & 63, wv = tid >> 6;
  const u32* sbb = sb + b * NANCH;

  // Phase 1: coarse histogram bits[31:22]
  hist[tid] = 0;
  __syncthreads();
  for (int n = tid; n < NANCH; n += 1024) atomicAdd(&hist[sbb[n] >> 22], 1u);
  __syncthreads();
  u32 h = hist[tid];
  u32 s = h;
  for (int d = 1; d < 64; d <<= 1) { u32 y = (u32)__shfl_down((int)s, d); if (lane + d < 64) s += y; }
  if (lane == 0) wtot[wv] = s;
  hist[tid] = 0;
  __syncthreads();
  {
    u32 add = 0;
    for (int w2 = wv + 1; w2 < 16; ++w2) add += wtot[w2];
    s += add;
  }
  if (s >= (u32)KDET && s - h < (u32)KDET) { s_T1 = tid; s_above = (int)(s - h); }
  __syncthreads();
  const int T1 = s_T1; const int above = s_above;

  // Phase 2: fine histogram bits[21:12] within bin T1
  for (int n = tid; n < NANCH; n += 1024) {
    u32 bits = sbb[n];
    if ((int)(bits >> 22) == T1) atomicAdd(&hist[(bits >> 12) & 1023u], 1u);
  }
  __syncthreads();
  h = hist[tid];
  s = h;
  for (int d = 1; d < 64; d <<= 1) { u32 y = (u32)__shfl_down((int)s, d); if (lane + d < 64) s += y; }
  if (lane == 0) wtot[wv] = s;
  __syncthreads();
  {
    u32 add = 0;
    for (int w2 = wv + 1; w2 < 16; ++w2) add += wtot[w2];
    s += add;
  }
  if (above + (int)s >= KDET && above + (int)(s - h) < KDET) s_T2 = tid;
  if (tid == 0) s_cnt = 0;
  __syncthreads();
  const int T2 = s_T2;

  // Phase 3: collect candidate keys (desc score, asc index tie-break)
  for (int n = tid; n < NANCH; n += 1024) {
    u32 bits = sbb[n];
    int c1 = (int)(bits >> 22);
    bool cand = (c1 > T1) || (c1 == T1 && (int)((bits >> 12) & 1023u) >= T2);
    if (cand) {
      int pos = atomicAdd(&s_cnt, 1);
      if (pos < 2048) keys[pos] = ((u64)bits << 32) | (u64)(u32)(~(u32)n);
    }
  }
  __syncthreads();
  int C = s_cnt; if (C > 2048) C = 2048;

  // Phase 4: rank-by-counting; winners (rank < 1000) gather + stage
  float mymax = -3.4e38f;
  int posA = -1, clA = 0; float scA = 0; float4 boxA = make_float4(0, 0, 0, 0);
  int posB = -1, clB = 0; float scB = 0; float4 boxB = make_float4(0, 0, 0, 0);
  for (int t = tid; t < C; t += 1024) {
    u64 key = keys[t];
    int cnt = 0;
    for (int ss = 0; ss < C; ++ss) cnt += (keys[ss] > key) ? 1 : 0;
    if (cnt < KDET) {
      u32 bits = (u32)(key >> 32);
      int n = (int)(~(u32)(key & 0xFFFFFFFFull));
      float score = __uint_as_float(bits);
      int clsv = (int)cl8[b * NANCH + n] + 1;
      int l, hh, ww; decode_anchor(n, l, hh, ww);
      const float* rp; int W, ST, HF;
      switch (l) {
        case 0: rp = reg0; W = 128; ST = 8;   HF = 4;  break;
        case 1: rp = reg1; W = 64;  ST = 16;  HF = 8;  break;
        case 2: rp = reg2; W = 32;  ST = 32;  HF = 16; break;
        case 3: rp = reg3; W = 16;  ST = 64;  HF = 32; break;
        default: rp = reg4; W = 8;  ST = 128; HF = 64; break;
      }
      int hw; switch (l) { case 0: hw = 12800; break; case 1: hw = 3200; break;
                           case 2: hw = 800; break; case 3: hw = 208; break; default: hw = 56; }
      float cx = (float)(ww * ST + HF);
      float cy = (float)(hh * ST + HF);
      const float* rb = rp + (size_t)b * 4 * hw + hh * W + ww;
      float r0 = rb[0], r1 = rb[hw], r2 = rb[2 * hw], r3 = rb[3 * hw];
      float4 bx = make_float4(cx - r0, cy - r1, cx + r2, cy + r3);
      mymax = fmaxf(mymax, fmaxf(fmaxf(bx.x, bx.y), fmaxf(bx.z, bx.w)));
      if (posA < 0) { posA = cnt; scA = score; clA = clsv; boxA = bx; }
      else          { posB = cnt; scB = score; clB = clsv; boxB = bx; }
    }
  }

  // Phase 5: max coordinate over all 1000 topk boxes
  {
    float wm = mymax;
    for (int d = 1; d < 64; d <<= 1) { float y = __shfl_down(wm, d); if (lane + d < 64) wm = fmaxf(wm, y); }
    if (lane == 0) wmaxS[wv] = wm;
  }
  __syncthreads();
  float maxc = -3.4e38f;
  for (int w2 = 0; w2 < 16; ++w2) maxc = fmaxf(maxc, wmaxS[w2]);

  // Phase 6: winners write staging arrays
  if (posA >= 0) {
    int o = b * KDET + posA;
    scoreG[o] = scA; clsG[o] = clA; boxG[o] = boxA;
    float off = (float)clA * (maxc + 1.0f);
    float x1 = boxA.x + off, y1 = boxA.y + off, x2 = boxA.z + off, y2 = boxA.w + off;
    nbxG[o] = make_float4(x1, y1, x2, y2);
    areaG[o] = (x2 - x1 + 1.0f) * (y2 - y1 + 1.0f);
  }
  if (posB >= 0) {
    int o = b * KDET + posB;
    scoreG[o] = scB; clsG[o] = clB; boxG[o] = boxB;
    float off = (float)clB * (maxc + 1.0f);
    float x1 = boxB.x + off, y1 = boxB.y + off, x2 = boxB.z + off, y2 = boxB.w + off;
    nbxG[o] = make_float4(x1, y1, x2, y2);
    areaG[o] = (x2 - x1 + 1.0f) * (y2 - y1 + 1.0f);
  }
}

// ---------------- kernel 3: suppression matrix, full-GPU parallel ----------------
__global__ __launch_bounds__(256) void k_mat(
    const float4* __restrict__ nbxG, const float* __restrict__ areaG,
    u64* __restrict__ mat)
{
  __shared__ float4 nbxS[1024];
  __shared__ float areaS[1024];
  const int tid = threadIdx.x, lane = tid & 63, wv = tid >> 6;
  const int g = blockIdx.x, b = blockIdx.y;
  for (int i = tid; i < 1024; i += 256) {
    if (i < KDET) { nbxS[i] = nbxG[b * KDET + i]; areaS[i] = areaG[b * KDET + i]; }
    else          { nbxS[i] = make_float4(0, 0, 0, 0); areaS[i] = 0.0f; }
  }
  __syncthreads();
  u64* mrow = mat + (size_t)b * (KDET * 16);
  int start = g * 64, end = min(start + 64, KDET);
  for (int r = start + wv; r < end; r += 4) {
    float4 bi = nbxS[r];
    float ai = areaS[r];
    for (int wc = g; wc < 16; ++wc) {
      int j = (wc << 6) + lane;
      float4 bj = nbxS[j];
      float xmin = fmaxf(bi.x, bj.x);
      float ymin = fmaxf(bi.y, bj.y);
      float xmax = fminf(bi.z, bj.z);
      float ymax = fminf(bi.w, bj.w);
      float iw = fmaxf(xmax - xmin, 0.0f);
      float ih = fmaxf(ymax - ymin, 0.0f);
      float inter = iw * ih;
      float iou = inter / ((ai + areaS[j]) - inter);
      bool p = (j > r) && (j < KDET) && (iou > IOU_THR);
      u64 mm = __ballot(p);
      if (lane == 0) mrow[r * 16 + wc] = mm;
    }
  }
}

// ---------------- kernel 4: serial greedy scan + outputs ----------------
__global__ __launch_bounds__(1024) void k_nms(
    const u64* __restrict__ mat, const float* __restrict__ scoreG,
    const int* __restrict__ clsG, const float4* __restrict__ boxG,
    float* __restrict__ out)
{
  __shared__ u64 invw[16];
  __shared__ u64 supw[16];
  const int tid = threadIdx.x;
  const int b = blockIdx.x;
  float sc = (tid < KDET) ? scoreG[b * KDET + tid] : 0.0f;
  {
    bool inv = (tid >= KDET) || (sc < SCORE_THR);
    u64 mb = __ballot(inv);
    if ((tid & 63) == 0) invw[tid >> 6] = mb;
  }
  __syncthreads();
  if (tid < 64) {
    int lane = tid;
    u64 sup = (lane < 16) ? invw[lane] : 0ull;
    const u64* mrow = mat + (size_t)b * (KDET * 16);
    u64 buf[8];
#pragma unroll
    for (int p = 0; p < 8; ++p) buf[p] = (lane < 16) ? mrow[p * 16 + lane] : 0ull;
    for (int base = 0; base < KDET; base += 8) {
#pragma unroll
      for (int p = 0; p < 8; ++p) {
        int i = base + p;
        u64 sw = __shfl(sup, i >> 6);
        bool keep = ((sw >> (i & 63)) & 1ull) == 0ull;
        u64 row = (lane >= (i >> 6)) ? buf[p] : 0ull;   // words < i>>6 never written by k_mat
        int ip = i + 8;
        buf[p] = (ip < KDET && lane < 16) ? mrow[ip * 16 + lane] : 0ull;
        if (keep) sup |= row;
      }
    }
    if (lane < 16) supw[lane] = sup;
  }
  __syncthreads();
  if (tid < KDET) {
    bool kp = (sc >= SCORE_THR) && (((supw[tid >> 6] >> (tid & 63)) & 1ull) == 0ull);
    int o1 = b * KDET + tid;
    out[o1] = kp ? sc : 0.0f;
    out[BATCH * KDET + o1] = kp ? (float)clsG[o1] : 0.0f;
    float4 bx = boxG[o1];
    float* ob = out + 2 * BATCH * KDET + (size_t)o1 * 4;
    ob[0] = kp ? bx.x : 0.0f;
    ob[1] = kp ? bx.y : 0.0f;
    ob[2] = kp ? bx.z : 0.0f;
    ob[3] = kp ? bx.w : 0.0f;
  }
}

extern "C" void kernel_launch(void* const* d_in, const int* in_sizes, int n_in,
                              void* d_out, int out_size, void* d_ws, size_t ws_size,
                              hipStream_t stream) {
  const float* cls[5]; const float* ctr[5]; const float* reg[5];
  for (int i = 0; i < 5; ++i) {
    cls[i] = (const float*)d_in[3 * i + 0];
    ctr[i] = (const float*)d_in[3 * i + 1];
    reg[i] = (const float*)d_in[3 * i + 2];
  }
  char* ws = (char*)d_ws;
  // Overlay: sb+cl8 (dead after k_topk) share the region mat is written into by k_mat.
  u32* sb = (u32*)ws;                                   // 1,092,096 B
  unsigned char* cl8 = (unsigned char*)(ws + 1092096);  //   273,024 B
  u64* mat = (u64*)ws;                                  // 2,048,000 B (reuses sb+cl8)
  float4* nbxG  = (float4*)(ws + 2048000);              //   256,000 B
  float*  areaG = (float*) (ws + 2304000);              //    64,000 B
  float*  scoreG= (float*) (ws + 2368000);              //    64,000 B
  int*    clsG  = (int*)   (ws + 2432000);              //    64,000 B
  float4* boxG  = (float4*)(ws + 2496000);              //   256,000 B -> 2,752,000 total

  dim3 g1((NANCH + 255) / 256, BATCH);
  k_score<<<g1, 256, 0, stream>>>(cls[0], ctr[0], cls[1], ctr[1], cls[2], ctr[2],
                                  cls[3], ctr[3], cls[4], ctr[4], sb, cl8);
  k_topk<<<BATCH, 1024, 0, stream>>>(reg[0], reg[1], reg[2], reg[3], reg[4],
                                     sb, cl8, nbxG, areaG, scoreG, clsG, boxG);
  k_mat<<<dim3(16, BATCH), 256, 0, stream>>>(nbxG, areaG, mat);
  k_nms<<<BATCH, 1024, 0, stream>>>(mat, scoreG, clsG, boxG, (float*)d_out);
}

// Round 3
// 237.234 us; speedup vs baseline: 1.8778x; 1.5107x over previous
//
#include <hip/hip_runtime.h>
#include <stdint.h>

#define NANCH 17064
#define BATCH 16
#define NCLS 80
#define KDET 1000
#define SCORE_THR 0.05f
#define IOU_THR 0.6f

typedef unsigned long long u64;
typedef unsigned int u32;

__device__ __forceinline__ float sigf(float x) { return 1.0f / (1.0f + expf(-x)); }

__device__ __forceinline__ void decode_anchor(int n, int& l, int& h, int& w) {
  if (n < 12800)      { l = 0; h = n >> 7;               w = n & 127; }
  else if (n < 16000) { l = 1; int r = n - 12800; h = r >> 6; w = r & 63; }
  else if (n < 16800) { l = 2; int r = n - 16000; h = r >> 5; w = r & 31; }
  else if (n < 17008) { l = 3; int r = n - 16800; h = r >> 4; w = r & 15; }
  else                { l = 4; int r = n - 17008; h = r >> 3; w = r & 7; }
}

// ---------------- kernel 1: per-anchor scores ----------------
__global__ __launch_bounds__(256) void k_score(
    const float* __restrict__ cls0, const float* __restrict__ ctr0,
    const float* __restrict__ cls1, const float* __restrict__ ctr1,
    const float* __restrict__ cls2, const float* __restrict__ ctr2,
    const float* __restrict__ cls3, const float* __restrict__ ctr3,
    const float* __restrict__ cls4, const float* __restrict__ ctr4,
    u32* __restrict__ sb, unsigned char* __restrict__ cl8)
{
  int n = blockIdx.x * blockDim.x + threadIdx.x;
  if (n >= NANCH) return;
  int b = blockIdx.y;
  int l, h, w; decode_anchor(n, l, h, w);
  const float* cp; const float* tp; int H, W;
  switch (l) {
    case 0: cp = cls0; tp = ctr0; H = 100; W = 128; break;
    case 1: cp = cls1; tp = ctr1; H = 50;  W = 64;  break;
    case 2: cp = cls2; tp = ctr2; H = 25;  W = 32;  break;
    case 3: cp = cls3; tp = ctr3; H = 13;  W = 16;  break;
    default: cp = cls4; tp = ctr4; H = 7;  W = 8;   break;
  }
  int hw = H * W;
  const float* base = cp + (size_t)b * NCLS * hw + h * W + w;
  float ms = -1.0f; int am = 0;
  for (int c = 0; c < NCLS; ++c) {
    float s = sigf(base[(size_t)c * hw]);
    if (s > ms) { ms = s; am = c; }
  }
  float ct = sigf(tp[(size_t)b * hw + h * W + w]);
  float score = ms * ct;
  sb[b * NANCH + n] = __float_as_uint(score);
  cl8[b * NANCH + n] = (unsigned char)am;
}

// ---------------- kernel 2: top-1000 via radix-select + rank-by-counting ----------------
__global__ __launch_bounds__(1024) void k_topk(
    const float* __restrict__ reg0, const float* __restrict__ reg1,
    const float* __restrict__ reg2, const float* __restrict__ reg3,
    const float* __restrict__ reg4,
    const u32* __restrict__ sb, const unsigned char* __restrict__ cl8,
    float4* __restrict__ nbxG, float* __restrict__ areaG,
    float* __restrict__ scoreG, int* __restrict__ clsG, float4* __restrict__ boxG)
{
  __shared__ u32 hist[1024];
  __shared__ u32 wtot[16];
  __shared__ float wmaxS[16];
  __shared__ u64 keys[2048];
  __shared__ int s_T1, s_above, s_T2, s_cnt;

  const int tid = threadIdx.x;
  const int b = blockIdx.x;
  const int lane = tid & 63, wv = tid >> 6;
  const u32* sbb = sb + b * NANCH;

  // Phase 1: coarse histogram bits[31:22]
  hist[tid] = 0;
  __syncthreads();
  for (int n = tid; n < NANCH; n += 1024) atomicAdd(&hist[sbb[n] >> 22], 1u);
  __syncthreads();
  u32 h = hist[tid];
  u32 s = h;
  for (int d = 1; d < 64; d <<= 1) { u32 y = (u32)__shfl_down((int)s, d); if (lane + d < 64) s += y; }
  if (lane == 0) wtot[wv] = s;
  hist[tid] = 0;
  __syncthreads();
  {
    u32 add = 0;
    for (int w2 = wv + 1; w2 < 16; ++w2) add += wtot[w2];
    s += add;
  }
  if (s >= (u32)KDET && s - h < (u32)KDET) { s_T1 = tid; s_above = (int)(s - h); }
  __syncthreads();
  const int T1 = s_T1; const int above = s_above;

  // Phase 2: fine histogram bits[21:12] within bin T1
  for (int n = tid; n < NANCH; n += 1024) {
    u32 bits = sbb[n];
    if ((int)(bits >> 22) == T1) atomicAdd(&hist[(bits >> 12) & 1023u], 1u);
  }
  __syncthreads();
  h = hist[tid];
  s = h;
  for (int d = 1; d < 64; d <<= 1) { u32 y = (u32)__shfl_down((int)s, d); if (lane + d < 64) s += y; }
  if (lane == 0) wtot[wv] = s;
  __syncthreads();
  {
    u32 add = 0;
    for (int w2 = wv + 1; w2 < 16; ++w2) add += wtot[w2];
    s += add;
  }
  if (above + (int)s >= KDET && above + (int)(s - h) < KDET) s_T2 = tid;
  if (tid == 0) s_cnt = 0;
  __syncthreads();
  const int T2 = s_T2;

  // Phase 3: collect candidate keys (desc score, asc index tie-break)
  for (int n = tid; n < NANCH; n += 1024) {
    u32 bits = sbb[n];
    int c1 = (int)(bits >> 22);
    bool cand = (c1 > T1) || (c1 == T1 && (int)((bits >> 12) & 1023u) >= T2);
    if (cand) {
      int pos = atomicAdd(&s_cnt, 1);
      if (pos < 2048) keys[pos] = ((u64)bits << 32) | (u64)(u32)(~(u32)n);
    }
  }
  __syncthreads();
  int C = s_cnt; if (C > 2048) C = 2048;

  // Phase 4: rank-by-counting; winners (rank < 1000) gather + stage
  float mymax = -3.4e38f;
  int posA = -1, clA = 0; float scA = 0; float4 boxA = make_float4(0, 0, 0, 0);
  int posB = -1, clB = 0; float scB = 0; float4 boxB = make_float4(0, 0, 0, 0);
  for (int t = tid; t < C; t += 1024) {
    u64 key = keys[t];
    int cnt = 0;
    for (int ss = 0; ss < C; ++ss) cnt += (keys[ss] > key) ? 1 : 0;
    if (cnt < KDET) {
      u32 bits = (u32)(key >> 32);
      int n = (int)(~(u32)(key & 0xFFFFFFFFull));
      float score = __uint_as_float(bits);
      int clsv = (int)cl8[b * NANCH + n] + 1;
      int l, hh, ww; decode_anchor(n, l, hh, ww);
      const float* rp; int W, ST, HF;
      switch (l) {
        case 0: rp = reg0; W = 128; ST = 8;   HF = 4;  break;
        case 1: rp = reg1; W = 64;  ST = 16;  HF = 8;  break;
        case 2: rp = reg2; W = 32;  ST = 32;  HF = 16; break;
        case 3: rp = reg3; W = 16;  ST = 64;  HF = 32; break;
        default: rp = reg4; W = 8;  ST = 128; HF = 64; break;
      }
      int hw; switch (l) { case 0: hw = 12800; break; case 1: hw = 3200; break;
                           case 2: hw = 800; break; case 3: hw = 208; break; default: hw = 56; }
      float cx = (float)(ww * ST + HF);
      float cy = (float)(hh * ST + HF);
      const float* rb = rp + (size_t)b * 4 * hw + hh * W + ww;
      float r0 = rb[0], r1 = rb[hw], r2 = rb[2 * hw], r3 = rb[3 * hw];
      float4 bx = make_float4(cx - r0, cy - r1, cx + r2, cy + r3);
      mymax = fmaxf(mymax, fmaxf(fmaxf(bx.x, bx.y), fmaxf(bx.z, bx.w)));
      if (posA < 0) { posA = cnt; scA = score; clA = clsv; boxA = bx; }
      else          { posB = cnt; scB = score; clB = clsv; boxB = bx; }
    }
  }

  // Phase 5: max coordinate over all 1000 topk boxes
  {
    float wm = mymax;
    for (int d = 1; d < 64; d <<= 1) { float y = __shfl_down(wm, d); if (lane + d < 64) wm = fmaxf(wm, y); }
    if (lane == 0) wmaxS[wv] = wm;
  }
  __syncthreads();
  float maxc = -3.4e38f;
  for (int w2 = 0; w2 < 16; ++w2) maxc = fmaxf(maxc, wmaxS[w2]);

  // Phase 6: winners write staging arrays
  if (posA >= 0) {
    int o = b * KDET + posA;
    scoreG[o] = scA; clsG[o] = clA; boxG[o] = boxA;
    float off = (float)clA * (maxc + 1.0f);
    float x1 = boxA.x + off, y1 = boxA.y + off, x2 = boxA.z + off, y2 = boxA.w + off;
    nbxG[o] = make_float4(x1, y1, x2, y2);
    areaG[o] = (x2 - x1 + 1.0f) * (y2 - y1 + 1.0f);
  }
  if (posB >= 0) {
    int o = b * KDET + posB;
    scoreG[o] = scB; clsG[o] = clB; boxG[o] = boxB;
    float off = (float)clB * (maxc + 1.0f);
    float x1 = boxB.x + off, y1 = boxB.y + off, x2 = boxB.z + off, y2 = boxB.w + off;
    nbxG[o] = make_float4(x1, y1, x2, y2);
    areaG[o] = (x2 - x1 + 1.0f) * (y2 - y1 + 1.0f);
  }
}

// ---------------- kernel 3: TRANSPOSED suppression matrix ----------------
// matT[i][w] bit j: (j < i) && iou(i,j) > thr  -> suppressors of i
__global__ __launch_bounds__(256) void k_mat(
    const float4* __restrict__ nbxG, const float* __restrict__ areaG,
    u64* __restrict__ mat)
{
  __shared__ float4 nbxS[1024];
  __shared__ float areaS[1024];
  const int tid = threadIdx.x, lane = tid & 63, wv = tid >> 6;
  const int g = blockIdx.x, b = blockIdx.y;
  for (int i = tid; i < 1024; i += 256) {
    if (i < KDET) { nbxS[i] = nbxG[b * KDET + i]; areaS[i] = areaG[b * KDET + i]; }
    else          { nbxS[i] = make_float4(0, 0, 0, 0); areaS[i] = 0.0f; }
  }
  __syncthreads();
  u64* mrow = mat + (size_t)b * (KDET * 16);
  int start = g * 64, end = min(start + 64, KDET);
  for (int r = start + wv; r < end; r += 4) {
    float4 bi = nbxS[r];
    float ai = areaS[r];
    int wmax = r >> 6;  // == g
    for (int wc = 0; wc <= wmax; ++wc) {
      int j = (wc << 6) + lane;
      float4 bj = nbxS[j];
      float xmin = fmaxf(bi.x, bj.x);
      float ymin = fmaxf(bi.y, bj.y);
      float xmax = fminf(bi.z, bj.z);
      float ymax = fminf(bi.w, bj.w);
      float iw = fmaxf(xmax - xmin, 0.0f);
      float ih = fmaxf(ymax - ymin, 0.0f);
      float inter = iw * ih;
      float iou = inter / ((ai + areaS[j]) - inter);
      bool p = (j < r) && (iou > IOU_THR);
      u64 mm = __ballot(p);
      if (lane == 0) mrow[r * 16 + wc] = mm;
    }
  }
}

// ---------------- kernel 4: exact greedy NMS via Jacobi fixpoint + outputs ----------------
__global__ __launch_bounds__(1024) void k_nms(
    const u64* __restrict__ mat, const float* __restrict__ scoreG,
    const int* __restrict__ clsG, const float4* __restrict__ boxG,
    float* __restrict__ out)
{
  __shared__ u64 keptS[16];
  __shared__ int s_chg;
  const int tid = threadIdx.x;
  const int b = blockIdx.x;
  const int wv = tid >> 6, lane = tid & 63;

  float sc = (tid < KDET) ? scoreG[b * KDET + tid] : 0.0f;
  bool valid = (tid < KDET) && (sc >= SCORE_THR);

  // load my suppressor column into registers (words > tid>>6 were never written)
  u64 row[16];
  const u64* mrow = mat + (size_t)b * (KDET * 16) + (size_t)tid * 16;
  const int wtop = tid >> 6;
#pragma unroll
  for (int w = 0; w < 16; ++w)
    row[w] = (tid < KDET && w <= wtop) ? mrow[w] : 0ull;

  // init kept = valid
  {
    u64 mb = __ballot(valid);
    if (lane == 0) keptS[wv] = mb;
  }
  __syncthreads();

  // Jacobi iteration: kept_i = valid_i && !OR_{j<i}(kept_j && sup_ji).
  // Fixpoint is the exact sequential greedy NMS (unique solution of the
  // triangular recurrence); bit t is provably correct after t+1 iterations,
  // and the loop exits as soon as the mask is stable.
  for (int it = 0; it < KDET + 1; ++it) {
    u64 sup = 0;
#pragma unroll
    for (int w = 0; w < 16; ++w) sup |= keptS[w] & row[w];
    bool nk = valid && (sup == 0ull);
    u64 nw = __ballot(nk);
    if (tid == 0) s_chg = 0;
    __syncthreads();                 // all reads of keptS done; s_chg reset visible
    if (lane == 0) {
      if (nw != keptS[wv]) s_chg = 1;
      keptS[wv] = nw;
    }
    __syncthreads();
    if (s_chg == 0) break;           // uniform exit
  }

  // outputs (scores | classes | boxes), zeros where not kept
  if (tid < KDET) {
    bool kp = ((keptS[tid >> 6] >> (tid & 63)) & 1ull) != 0ull;
    int o1 = b * KDET + tid;
    out[o1] = kp ? sc : 0.0f;
    out[BATCH * KDET + o1] = kp ? (float)clsG[o1] : 0.0f;
    float4 bx = boxG[o1];
    float* ob = out + 2 * BATCH * KDET + (size_t)o1 * 4;
    ob[0] = kp ? bx.x : 0.0f;
    ob[1] = kp ? bx.y : 0.0f;
    ob[2] = kp ? bx.z : 0.0f;
    ob[3] = kp ? bx.w : 0.0f;
  }
}

extern "C" void kernel_launch(void* const* d_in, const int* in_sizes, int n_in,
                              void* d_out, int out_size, void* d_ws, size_t ws_size,
                              hipStream_t stream) {
  const float* cls[5]; const float* ctr[5]; const float* reg[5];
  for (int i = 0; i < 5; ++i) {
    cls[i] = (const float*)d_in[3 * i + 0];
    ctr[i] = (const float*)d_in[3 * i + 1];
    reg[i] = (const float*)d_in[3 * i + 2];
  }
  char* ws = (char*)d_ws;
  // Overlay: sb+cl8 (dead after k_topk) share the region mat is written into by k_mat.
  u32* sb = (u32*)ws;                                   // 1,092,096 B
  unsigned char* cl8 = (unsigned char*)(ws + 1092096);  //   273,024 B
  u64* mat = (u64*)ws;                                  // 2,048,000 B (reuses sb+cl8)
  float4* nbxG  = (float4*)(ws + 2048000);              //   256,000 B
  float*  areaG = (float*) (ws + 2304000);              //    64,000 B
  float*  scoreG= (float*) (ws + 2368000);              //    64,000 B
  int*    clsG  = (int*)   (ws + 2432000);              //    64,000 B
  float4* boxG  = (float4*)(ws + 2496000);              //   256,000 B -> 2,752,000 total

  dim3 g1((NANCH + 255) / 256, BATCH);
  k_score<<<g1, 256, 0, stream>>>(cls[0], ctr[0], cls[1], ctr[1], cls[2], ctr[2],
                                  cls[3], ctr[3], cls[4], ctr[4], sb, cl8);
  k_topk<<<BATCH, 1024, 0, stream>>>(reg[0], reg[1], reg[2], reg[3], reg[4],
                                     sb, cl8, nbxG, areaG, scoreG, clsG, boxG);
  k_mat<<<dim3(16, BATCH), 256, 0, stream>>>(nbxG, areaG, mat);
  k_nms<<<BATCH, 1024, 0, stream>>>(mat, scoreG, clsG, boxG, (float*)d_out);
}

// Round 4
// 201.447 us; speedup vs baseline: 2.2114x; 1.1776x over previous
//
#include <hip/hip_runtime.h>
#include <stdint.h>

#define NANCH 17064
#define BATCH 16
#define NCLS 80
#define KDET 1000
#define SCORE_THR 0.05f
#define IOU_THR 0.6f

typedef unsigned long long u64;
typedef unsigned int u32;

__device__ __forceinline__ float sigf(float x) { return 1.0f / (1.0f + expf(-x)); }

__device__ __forceinline__ void decode_anchor(int n, int& l, int& h, int& w) {
  if (n < 12800)      { l = 0; h = n >> 7;               w = n & 127; }
  else if (n < 16000) { l = 1; int r = n - 12800; h = r >> 6; w = r & 63; }
  else if (n < 16800) { l = 2; int r = n - 16000; h = r >> 5; w = r & 31; }
  else if (n < 17008) { l = 3; int r = n - 16800; h = r >> 4; w = r & 15; }
  else                { l = 4; int r = n - 17008; h = r >> 3; w = r & 7; }
}

// encode float for monotone u32 atomicMax
__device__ __forceinline__ u32 fenc(float f) {
  u32 u = __float_as_uint(f);
  return (u & 0x80000000u) ? ~u : (u | 0x80000000u);
}
__device__ __forceinline__ float fdec(u32 e) {
  u32 u = (e & 0x80000000u) ? (e ^ 0x80000000u) : ~e;
  return __uint_as_float(u);
}

// ---------------- kernel 1: per-anchor scores ----------------
__global__ __launch_bounds__(256) void k_score(
    const float* __restrict__ cls0, const float* __restrict__ ctr0,
    const float* __restrict__ cls1, const float* __restrict__ ctr1,
    const float* __restrict__ cls2, const float* __restrict__ ctr2,
    const float* __restrict__ cls3, const float* __restrict__ ctr3,
    const float* __restrict__ cls4, const float* __restrict__ ctr4,
    u32* __restrict__ sb, unsigned char* __restrict__ cl8)
{
  int n = blockIdx.x * blockDim.x + threadIdx.x;
  if (n >= NANCH) return;
  int b = blockIdx.y;
  int l, h, w; decode_anchor(n, l, h, w);
  const float* cp; const float* tp; int H, W;
  switch (l) {
    case 0: cp = cls0; tp = ctr0; H = 100; W = 128; break;
    case 1: cp = cls1; tp = ctr1; H = 50;  W = 64;  break;
    case 2: cp = cls2; tp = ctr2; H = 25;  W = 32;  break;
    case 3: cp = cls3; tp = ctr3; H = 13;  W = 16;  break;
    default: cp = cls4; tp = ctr4; H = 7;  W = 8;   break;
  }
  int hw = H * W;
  const float* base = cp + (size_t)b * NCLS * hw + h * W + w;
  float ms = -1.0f; int am = 0;
  for (int c = 0; c < NCLS; ++c) {
    float s = sigf(base[(size_t)c * hw]);
    if (s > ms) { ms = s; am = c; }
  }
  float ct = sigf(tp[(size_t)b * hw + h * W + w]);
  float score = ms * ct;
  sb[b * NANCH + n] = __float_as_uint(score);
  cl8[b * NANCH + n] = (unsigned char)am;
}

// ---------------- kernel 2: radix thresholds + candidate compaction ----------------
__global__ __launch_bounds__(1024) void k_topk(
    const u32* __restrict__ sb,
    u64* __restrict__ candG, int* __restrict__ cntG, u32* __restrict__ maxcG)
{
  __shared__ u32 hist[1024];
  __shared__ u32 wtot[16];
  __shared__ int s_T1, s_above, s_T2, s_cnt;

  const int tid = threadIdx.x;
  const int b = blockIdx.x;
  const int lane = tid & 63, wv = tid >> 6;
  const u32* sbb = sb + b * NANCH;

  // Phase 1: coarse histogram bits[31:22]
  hist[tid] = 0;
  __syncthreads();
  for (int n = tid; n < NANCH; n += 1024) atomicAdd(&hist[sbb[n] >> 22], 1u);
  __syncthreads();
  u32 h = hist[tid];
  u32 s = h;
  for (int d = 1; d < 64; d <<= 1) { u32 y = (u32)__shfl_down((int)s, d); if (lane + d < 64) s += y; }
  if (lane == 0) wtot[wv] = s;
  hist[tid] = 0;
  __syncthreads();
  {
    u32 add = 0;
    for (int w2 = wv + 1; w2 < 16; ++w2) add += wtot[w2];
    s += add;
  }
  if (s >= (u32)KDET && s - h < (u32)KDET) { s_T1 = tid; s_above = (int)(s - h); }
  __syncthreads();
  const int T1 = s_T1; const int above = s_above;

  // Phase 2: fine histogram bits[21:12] within bin T1
  for (int n = tid; n < NANCH; n += 1024) {
    u32 bits = sbb[n];
    if ((int)(bits >> 22) == T1) atomicAdd(&hist[(bits >> 12) & 1023u], 1u);
  }
  __syncthreads();
  h = hist[tid];
  s = h;
  for (int d = 1; d < 64; d <<= 1) { u32 y = (u32)__shfl_down((int)s, d); if (lane + d < 64) s += y; }
  if (lane == 0) wtot[wv] = s;
  __syncthreads();
  {
    u32 add = 0;
    for (int w2 = wv + 1; w2 < 16; ++w2) add += wtot[w2];
    s += add;
  }
  if (above + (int)s >= KDET && above + (int)(s - h) < KDET) s_T2 = tid;
  if (tid == 0) s_cnt = 0;
  __syncthreads();
  const int T2 = s_T2;

  // Phase 3: compact candidates to global
  for (int n = tid; n < NANCH; n += 1024) {
    u32 bits = sbb[n];
    int c1 = (int)(bits >> 22);
    bool cand = (c1 > T1) || (c1 == T1 && (int)((bits >> 12) & 1023u) >= T2);
    if (cand) {
      int pos = atomicAdd(&s_cnt, 1);
      if (pos < 2048) candG[b * 2048 + pos] = ((u64)bits << 32) | (u64)(u32)(~(u32)n);
    }
  }
  __syncthreads();
  if (tid == 0) {
    int C = s_cnt; if (C > 2048) C = 2048;
    cntG[b] = C;
    maxcG[b] = 0u;  // encoded -inf floor
  }
}

// ---------------- kernel 3: rank candidates, winners stage box/score/class ----------------
__global__ __launch_bounds__(256) void k_rank(
    const float* __restrict__ reg0, const float* __restrict__ reg1,
    const float* __restrict__ reg2, const float* __restrict__ reg3,
    const float* __restrict__ reg4,
    const unsigned char* __restrict__ cl8,
    const u64* __restrict__ candG, const int* __restrict__ cntG,
    float* __restrict__ scoreG, int* __restrict__ clsG, float4* __restrict__ boxG,
    u32* __restrict__ maxcG)
{
  __shared__ ulonglong2 keys2[1024];
  const int tid = threadIdx.x;
  const int c = blockIdx.x;   // 0..7
  const int b = blockIdx.y;
  const int lane = tid & 63;
  const int C = cntG[b];
  const u64* cand = candG + b * 2048;

  for (int i = tid; i < 1024; i += 256) {
    int i0 = 2 * i, i1 = 2 * i + 1;
    ulonglong2 v;
    v.x = (i0 < C) ? cand[i0] : 0ull;
    v.y = (i1 < C) ? cand[i1] : 0ull;
    keys2[i] = v;
  }
  __syncthreads();

  const int idx = c * 256 + tid;
  const bool active = (idx < C);
  u64 key = active ? cand[idx] : 0ull;

  int cnt = 0;
  const int Cp2 = ((C + 7) >> 3) << 2;   // ulonglong2 count, multiple of 4, covers C
  for (int s = 0; s < Cp2; s += 4) {
    ulonglong2 a0 = keys2[s], a1 = keys2[s + 1], a2 = keys2[s + 2], a3 = keys2[s + 3];
    cnt += (a0.x > key) + (a0.y > key) + (a1.x > key) + (a1.y > key)
         + (a2.x > key) + (a2.y > key) + (a3.x > key) + (a3.y > key);
  }

  u32 enc = 0u;
  if (active && cnt < KDET) {
    u32 bits = (u32)(key >> 32);
    int n = (int)(~(u32)(key & 0xFFFFFFFFull));
    float score = __uint_as_float(bits);
    int clsv = (int)cl8[b * NANCH + n] + 1;
    int l, hh, ww; decode_anchor(n, l, hh, ww);
    const float* rp; int W, ST, HF, hw;
    switch (l) {
      case 0: rp = reg0; W = 128; ST = 8;   HF = 4;  hw = 12800; break;
      case 1: rp = reg1; W = 64;  ST = 16;  HF = 8;  hw = 3200;  break;
      case 2: rp = reg2; W = 32;  ST = 32;  HF = 16; hw = 800;   break;
      case 3: rp = reg3; W = 16;  ST = 64;  HF = 32; hw = 208;   break;
      default: rp = reg4; W = 8;  ST = 128; HF = 64; hw = 56;    break;
    }
    float cx = (float)(ww * ST + HF);
    float cy = (float)(hh * ST + HF);
    const float* rb = rp + (size_t)b * 4 * hw + hh * W + ww;
    float r0 = rb[0], r1 = rb[hw], r2 = rb[2 * hw], r3 = rb[3 * hw];
    float4 bx = make_float4(cx - r0, cy - r1, cx + r2, cy + r3);
    int o = b * KDET + cnt;
    scoreG[o] = score; clsG[o] = clsv; boxG[o] = bx;
    enc = fenc(fmaxf(fmaxf(bx.x, bx.y), fmaxf(bx.z, bx.w)));
  }
  // wave-level max reduction of enc, one atomic per wave
  for (int d = 32; d > 0; d >>= 1) {
    u32 o = (u32)__shfl_xor((int)enc, d);
    enc = (o > enc) ? o : enc;
  }
  if (lane == 0 && enc != 0u) atomicMax(maxcG + b, enc);
}

// ---------------- kernel 4: transposed suppression matrix, register-only tiles ----------------
// matT[i][wc] bit j: (j < i) && iou(i,j) > thr
__global__ __launch_bounds__(256) void k_mat(
    const float4* __restrict__ boxG, const int* __restrict__ clsG,
    const u32* __restrict__ maxcG, u64* __restrict__ mat)
{
  const int tid = threadIdx.x, lane = tid & 63, wv = tid >> 6;
  const int b = blockIdx.y;
  const int tile = blockIdx.x * 4 + wv;
  if (tile >= 136) return;
  // triangular decode: tile = rt*(rt+1)/2 + wc, wc <= rt
  int rt = 0, rem = tile;
  while (rem >= rt + 1) { rem -= rt + 1; ++rt; }
  const int wc = rem;

  const float scale = fdec(maxcG[b]) + 1.0f;

  // column box j (per-lane, registers)
  const int j = (wc << 6) + lane;
  float jx1 = 0, jy1 = 0, jx2 = 0, jy2 = 0, aj = 0;
  if (j < KDET) {
    float4 bj = boxG[b * KDET + j];
    float off = (float)clsG[b * KDET + j] * scale;
    jx1 = bj.x + off; jy1 = bj.y + off; jx2 = bj.z + off; jy2 = bj.w + off;
    aj = (jx2 - jx1 + 1.0f) * (jy2 - jy1 + 1.0f);
  }
  // row boxes rt*64+lane (per-lane, broadcast by shfl below)
  const int ri = (rt << 6) + lane;
  float ix1 = 0, iy1 = 0, ix2 = 0, iy2 = 0;
  if (ri < KDET) {
    float4 bi = boxG[b * KDET + ri];
    float off = (float)clsG[b * KDET + ri] * scale;
    ix1 = bi.x + off; iy1 = bi.y + off; ix2 = bi.z + off; iy2 = bi.w + off;
  }

  u64 myword = 0ull;
  for (int r = 0; r < 64; ++r) {
    float x1 = __shfl(ix1, r), y1 = __shfl(iy1, r);
    float x2 = __shfl(ix2, r), y2 = __shfl(iy2, r);
    float ai = (x2 - x1 + 1.0f) * (y2 - y1 + 1.0f);
    int row = (rt << 6) + r;
    float xmin = fmaxf(x1, jx1), ymin = fmaxf(y1, jy1);
    float xmax = fminf(x2, jx2), ymax = fminf(y2, jy2);
    float inter = fmaxf(xmax - xmin, 0.0f) * fmaxf(ymax - ymin, 0.0f);
    float iou = inter / ((ai + aj) - inter);
    bool p = (j < row) && (j < KDET) && (iou > IOU_THR);
    u64 mm = __ballot(p);
    if (lane == r) myword = mm;
  }
  const int rowl = (rt << 6) + lane;
  if (rowl < KDET) mat[(size_t)b * (KDET * 16) + rowl * 16 + wc] = myword;
}

// ---------------- kernel 5: exact greedy NMS via Jacobi fixpoint + outputs ----------------
__global__ __launch_bounds__(1024) void k_nms(
    const u64* __restrict__ mat, const float* __restrict__ scoreG,
    const int* __restrict__ clsG, const float4* __restrict__ boxG,
    float* __restrict__ out)
{
  __shared__ u64 keptS[16];
  __shared__ int s_chg;
  const int tid = threadIdx.x;
  const int b = blockIdx.x;
  const int wv = tid >> 6, lane = tid & 63;

  float sc = (tid < KDET) ? scoreG[b * KDET + tid] : 0.0f;
  bool valid = (tid < KDET) && (sc >= SCORE_THR);

  u64 row[16];
  const u64* mrow = mat + (size_t)b * (KDET * 16) + (size_t)tid * 16;
  const int wtop = tid >> 6;
#pragma unroll
  for (int w = 0; w < 16; ++w)
    row[w] = (tid < KDET && w <= wtop) ? mrow[w] : 0ull;

  {
    u64 mb = __ballot(valid);
    if (lane == 0) keptS[wv] = mb;
  }
  __syncthreads();

  for (int it = 0; it < KDET + 1; ++it) {
    u64 sup = 0;
#pragma unroll
    for (int w = 0; w < 16; ++w) sup |= keptS[w] & row[w];
    bool nk = valid && (sup == 0ull);
    u64 nw = __ballot(nk);
    if (tid == 0) s_chg = 0;
    __syncthreads();
    if (lane == 0) {
      if (nw != keptS[wv]) s_chg = 1;
      keptS[wv] = nw;
    }
    __syncthreads();
    if (s_chg == 0) break;
  }

  if (tid < KDET) {
    bool kp = ((keptS[tid >> 6] >> (tid & 63)) & 1ull) != 0ull;
    int o1 = b * KDET + tid;
    out[o1] = kp ? sc : 0.0f;
    out[BATCH * KDET + o1] = kp ? (float)clsG[o1] : 0.0f;
    float4 bx = boxG[o1];
    float* ob = out + 2 * BATCH * KDET + (size_t)o1 * 4;
    ob[0] = kp ? bx.x : 0.0f;
    ob[1] = kp ? bx.y : 0.0f;
    ob[2] = kp ? bx.z : 0.0f;
    ob[3] = kp ? bx.w : 0.0f;
  }
}

extern "C" void kernel_launch(void* const* d_in, const int* in_sizes, int n_in,
                              void* d_out, int out_size, void* d_ws, size_t ws_size,
                              hipStream_t stream) {
  const float* cls[5]; const float* ctr[5]; const float* reg[5];
  for (int i = 0; i < 5; ++i) {
    cls[i] = (const float*)d_in[3 * i + 0];
    ctr[i] = (const float*)d_in[3 * i + 1];
    reg[i] = (const float*)d_in[3 * i + 2];
  }
  char* ws = (char*)d_ws;
  // mat region (0 .. 2,048,000) is overlaid by sb/cl8/candG, all dead before k_mat writes.
  u32* sb   = (u32*)ws;                                  // 1,092,096 B
  unsigned char* cl8 = (unsigned char*)(ws + 1092096);   //   273,024 B (dead after k_rank)
  u64* candG = (u64*)(ws + 1365120);                     //   262,144 B (dead after k_rank)
  u64* mat  = (u64*)ws;                                  // 2,048,000 B
  float*  scoreG = (float*) (ws + 2048000);              //    64,000 B
  int*    clsG   = (int*)   (ws + 2112000);              //    64,000 B
  float4* boxG   = (float4*)(ws + 2176000);              //   256,000 B
  int*    cntG   = (int*)   (ws + 2432000);              //        64 B
  u32*    maxcG  = (u32*)   (ws + 2432064);              //        64 B

  dim3 g1((NANCH + 255) / 256, BATCH);
  k_score<<<g1, 256, 0, stream>>>(cls[0], ctr[0], cls[1], ctr[1], cls[2], ctr[2],
                                  cls[3], ctr[3], cls[4], ctr[4], sb, cl8);
  k_topk<<<BATCH, 1024, 0, stream>>>(sb, candG, cntG, maxcG);
  k_rank<<<dim3(8, BATCH), 256, 0, stream>>>(reg[0], reg[1], reg[2], reg[3], reg[4],
                                             cl8, candG, cntG, scoreG, clsG, boxG, maxcG);
  k_mat<<<dim3(34, BATCH), 256, 0, stream>>>(boxG, clsG, maxcG, mat);
  k_nms<<<BATCH, 1024, 0, stream>>>(mat, scoreG, clsG, boxG, (float*)d_out);
}